// Round 1
// baseline (1696.952 us; speedup 1.0000x reference)
//
#include <hip/hip_runtime.h>
#include <math.h>

#define NPIX 1024
#define NBOX 9216
#define MASK_STRIDE 144   // u64 words per mask row (9216/64)

// ---------------- workspace layout (bytes) ----------------
#define O_PART     0u           // 4 * 262144 f32 = 4 MiB  (conv1 K-split partials)
#define O_H        4194304u     // 262144 f32 (hidden activations)
#define O_BOXES    5242880u     // 9216*4 f32
#define O_CONF     5390336u     // 9216 f32
#define O_KEYS     5427200u     // 9216 u64
#define O_RPART    5500928u     // 36*9216 i32
#define O_ORDER    6828032u     // 9216 i32
#define O_SBOX     6864896u     // 9216*4 f32 (boxes in sorted order)
#define O_SAREA    7012352u     // 9216 f32
#define O_VCNT     7049216u     // 1 i32
#define O_MASK     7049232u     // 9216*144 u64 = 10,616,832
#define O_KEEPW    17666064u    // 192 u64
// total ~17.7 MB

// ============ conv1: 3x3 SAME, 1280->256, fp32, K-split x4 ============
// grid (32,4,4): x = co-group (8 ch), y = 16x16 pixel patch, z = K chunk (320 ci)
// Weights are wave-uniform -> scalar loads (broadcast); LDS holds 8ci x 18x18 halo.
__global__ __launch_bounds__(256) void conv1_kernel(const float* __restrict__ feat,
                                                    const float* __restrict__ w1,
                                                    float* __restrict__ partial) {
    const int cg = blockIdx.x;          // 0..31
    const int pg = blockIdx.y;          // 0..3
    const int kc = blockIdx.z;          // 0..3
    const int tid = threadIdx.x;
    const int tx = tid & 15, ty = tid >> 4;
    const int x0 = (pg & 1) * 16, y0 = (pg >> 1) * 16;
    const int ci_base = kc * 320;

    __shared__ float sf[8][18][18];     // 10.4 KB
    float acc[8];
#pragma unroll
    for (int i = 0; i < 8; ++i) acc[i] = 0.f;

    for (int cs = 0; cs < 320; cs += 8) {
        __syncthreads();
        // stage 8 x 18x18 halo (zero-padded SAME borders)
        for (int e = tid; e < 8 * 324; e += 256) {
            int cil = e / 324;
            int rem = e - cil * 324;
            int yy = rem / 18;
            int xx = rem - yy * 18;
            int gy = y0 - 1 + yy, gx = x0 - 1 + xx;
            float v = 0.f;
            if ((unsigned)gy < 32u && (unsigned)gx < 32u)
                v = feat[(ci_base + cs + cil) * NPIX + gy * 32 + gx];
            sf[cil][yy][xx] = v;
        }
        __syncthreads();

#pragma unroll
        for (int cil = 0; cil < 8; ++cil) {
            float f[9];
#pragma unroll
            for (int dy = 0; dy < 3; ++dy)
#pragma unroll
                for (int dx = 0; dx < 3; ++dx)
                    f[dy * 3 + dx] = sf[cil][ty + dy][tx + dx];
            const float* wp = w1 + ((size_t)(cg * 8) * 1280 + (ci_base + cs + cil)) * 9;
#pragma unroll
            for (int co = 0; co < 8; ++co) {
#pragma unroll
                for (int t = 0; t < 9; ++t)
                    acc[co] = fmaf(f[t], wp[(size_t)co * 1280 * 9 + t], acc[co]);
            }
        }
    }
    const int pix = (y0 + ty) * 32 + (x0 + tx);
#pragma unroll
    for (int co = 0; co < 8; ++co)
        partial[(size_t)kc * 262144 + (cg * 8 + co) * NPIX + pix] = acc[co];
}

// ============ reduce partials + bias + leaky relu ============
__global__ __launch_bounds__(256) void conv1_reduce(const float* __restrict__ partial,
                                                    const float* __restrict__ b1,
                                                    float* __restrict__ h) {
    int i = blockIdx.x * 256 + threadIdx.x;   // 262144 = co*1024 + pix
    float s = partial[i] + partial[262144 + i] + partial[2 * 262144 + i] +
              partial[3 * 262144 + i] + b1[i >> 10];
    h[i] = s > 0.f ? s : 0.01f * s;
}

// ============ conv2 (1x1) + sigmoid + box decode + sort keys ============
// thread gid: a = gid>>10 (wave-uniform -> scalar w2 loads), p = gid&1023
__global__ __launch_bounds__(256) void conv2_decode(const float* __restrict__ h,
                                                    const float* __restrict__ w2,
                                                    const float* __restrict__ b2,
                                                    const float* __restrict__ anchors,
                                                    float* __restrict__ boxes,
                                                    float* __restrict__ conf_arr,
                                                    unsigned long long* __restrict__ keys,
                                                    int* __restrict__ Vcnt) {
    int gid = blockIdx.x * 256 + threadIdx.x;   // 9216
    int a = gid >> 10, p = gid & 1023;
    const float* wc0 = w2 + (size_t)(a * 6 + 0) * 256;
    const float* wc2 = w2 + (size_t)(a * 6 + 2) * 256;
    const float* wc3 = w2 + (size_t)(a * 6 + 3) * 256;
    const float* wc4 = w2 + (size_t)(a * 6 + 4) * 256;
    const float* wc5 = w2 + (size_t)(a * 6 + 5) * 256;
    float s0 = b2[a * 6 + 0], s2 = b2[a * 6 + 2], s3 = b2[a * 6 + 3],
          s4 = b2[a * 6 + 4], s5 = b2[a * 6 + 5];
    for (int ci = 0; ci < 256; ++ci) {
        float hv = h[ci * NPIX + p];
        s0 = fmaf(hv, wc0[ci], s0);
        s2 = fmaf(hv, wc2[ci], s2);
        s3 = fmaf(hv, wc3[ci], s3);
        s4 = fmaf(hv, wc4[ci], s4);
        s5 = fmaf(hv, wc5[ci], s5);
    }
    float conf = 1.f / (1.f + expf(-s0));
    float x = (float)(p & 31), y = (float)(p >> 5);
    float cx = x + 0.5f, cy = y + 0.5f;
    float aw = anchors[a * 2 + 0], ah = anchors[a * 2 + 1];
    float pcx = cx + s2 * aw, pcy = cy + s3 * ah;
    float pw = aw * expf(s4), ph = ah * expf(s5);
    int idx = p * 9 + a;   // (y,x,a) flat order
    boxes[idx * 4 + 0] = pcx - pw / 2.f;
    boxes[idx * 4 + 1] = pcy - ph / 2.f;
    boxes[idx * 4 + 2] = pcx + pw / 2.f;
    boxes[idx * 4 + 3] = pcy + ph / 2.f;
    conf_arr[idx] = conf;
    bool valid = conf > 0.5f;
    float score = valid ? conf : -1.0f;
    unsigned int sb = __float_as_uint(score);
    sb = (sb & 0x80000000u) ? ~sb : (sb | 0x80000000u);   // order-preserving map
    keys[idx] = ((unsigned long long)sb << 32) | (unsigned int)(~idx); // desc score, asc idx
    if (valid) atomicAdd(Vcnt, 1);
}

// ============ rank (stable argsort) via pairwise count, j-split ============
__global__ __launch_bounds__(256) void rank_partial(const unsigned long long* __restrict__ keys,
                                                    int* __restrict__ rpart) {
    __shared__ unsigned long long sk[256];
    int i = blockIdx.x * 256 + threadIdx.x;
    sk[threadIdx.x] = keys[blockIdx.y * 256 + threadIdx.x];
    __syncthreads();
    unsigned long long ki = keys[i];
    int c = 0;
#pragma unroll 8
    for (int j = 0; j < 256; ++j) c += (sk[j] > ki) ? 1 : 0;
    rpart[blockIdx.y * NBOX + i] = c;
}

__global__ __launch_bounds__(256) void rank_reduce(const int* __restrict__ rpart,
                                                   int* __restrict__ order) {
    int i = blockIdx.x * 256 + threadIdx.x;
    int r = 0;
    for (int b = 0; b < 36; ++b) r += rpart[b * NBOX + i];
    order[r] = i;
}

// ============ gather boxes into sorted order + areas ============
__global__ __launch_bounds__(256) void gather_sorted(const int* __restrict__ order,
                                                     const float* __restrict__ boxes,
                                                     float* __restrict__ sbox,
                                                     float* __restrict__ sarea) {
    int p = blockIdx.x * 256 + threadIdx.x;
    int o = order[p];
    float x1 = boxes[o * 4 + 0], y1 = boxes[o * 4 + 1];
    float x2 = boxes[o * 4 + 2], y2 = boxes[o * 4 + 3];
    sbox[p * 4 + 0] = x1; sbox[p * 4 + 1] = y1;
    sbox[p * 4 + 2] = x2; sbox[p * 4 + 3] = y2;
    sarea[p] = fmaxf(x2 - x1, 0.f) * fmaxf(y2 - y1, 0.f);
}

// ============ suppression bitmask (triangle words only) ============
__global__ __launch_bounds__(256) void nms_mask(const float* __restrict__ sbox,
                                                const float* __restrict__ sarea,
                                                const int* __restrict__ Vp,
                                                unsigned long long* __restrict__ mask) {
    int i = blockIdx.x;
    int V = *Vp;
    if (i >= V) return;
    float x1i = sbox[i * 4 + 0], y1i = sbox[i * 4 + 1];
    float x2i = sbox[i * 4 + 2], y2i = sbox[i * 4 + 3];
    float ai = sarea[i];
    int nchunk = (V + 255) >> 8;
    for (int c = (i >> 8); c < nchunk; ++c) {
        int j = c * 256 + threadIdx.x;
        bool bit = false;
        if (j < V) {
            float x1j = sbox[j * 4 + 0], y1j = sbox[j * 4 + 1];
            float x2j = sbox[j * 4 + 2], y2j = sbox[j * 4 + 3];
            float iw = fmaxf(fminf(x2i, x2j) - fmaxf(x1i, x1j), 0.f);
            float ih = fmaxf(fminf(y2i, y2j) - fmaxf(y1i, y1j), 0.f);
            float inter = iw * ih;
            float iou = inter / (ai + sarea[j] - inter + 1e-8f);
            bit = iou > 0.7f;
        }
        unsigned long long b = __ballot(bit);
        if ((threadIdx.x & 63) == 0)
            mask[(size_t)i * MASK_STRIDE + c * 4 + (threadIdx.x >> 6)] = b;
    }
}

// ============ serial greedy scan: one wave, remv in registers ============
__global__ __launch_bounds__(64) void nms_scan(const unsigned long long* __restrict__ mask,
                                               const int* __restrict__ Vp,
                                               unsigned long long* __restrict__ keepw) {
    int lane = threadIdx.x;
    int V = *Vp;
    unsigned long long r0 = 0, r1 = 0, r2 = 0, k0 = 0, k1 = 0, k2 = 0;
    for (int i = 0; i < V; ++i) {
        const unsigned long long* row = mask + (size_t)i * MASK_STRIDE;
        unsigned long long m0 = row[lane];
        unsigned long long m1 = row[lane + 64];
        unsigned long long m2 = row[lane + 128];   // bits >= 8192 region of 12288-bit remv
        int w = i >> 6;
        int src = w & 63;
        int rr = w >> 6;
        unsigned long long cur = (rr == 0) ? r0 : (rr == 1) ? r1 : r2;
        cur = __shfl(cur, src, 64);
        bool sup = (cur >> (i & 63)) & 1ull;
        if (!sup) { r0 |= m0; r1 |= m1; r2 |= m2; }
        if (lane == src && !sup) {
            unsigned long long bit = 1ull << (i & 63);
            if (rr == 0) k0 |= bit; else if (rr == 1) k1 |= bit; else k2 |= bit;
        }
    }
    keepw[lane] = k0;
    keepw[lane + 64] = k1;
    keepw[lane + 128] = k2;
}

// ============ final output write (all 9216 x 5) ============
__global__ __launch_bounds__(256) void finalize(const int* __restrict__ order,
                                                const int* __restrict__ Vp,
                                                const unsigned long long* __restrict__ keepw,
                                                const float* __restrict__ boxes,
                                                const float* __restrict__ conf_arr,
                                                float* __restrict__ out) {
    int p = blockIdx.x * 256 + threadIdx.x;   // sorted position
    int V = *Vp;
    int o = order[p];
    bool keep = false;
    if (p < V) keep = (keepw[p >> 6] >> (p & 63)) & 1ull;
    float k = keep ? 1.f : 0.f;
    out[o * 5 + 0] = boxes[o * 4 + 0] * k;
    out[o * 5 + 1] = boxes[o * 4 + 1] * k;
    out[o * 5 + 2] = boxes[o * 4 + 2] * k;
    out[o * 5 + 3] = boxes[o * 4 + 3] * k;
    out[o * 5 + 4] = conf_arr[o] * k;
}

extern "C" void kernel_launch(void* const* d_in, const int* in_sizes, int n_in,
                              void* d_out, int out_size, void* d_ws, size_t ws_size,
                              hipStream_t stream) {
    const float* feat    = (const float*)d_in[0];
    const float* anchors = (const float*)d_in[1];
    const float* w1      = (const float*)d_in[2];
    const float* b1      = (const float*)d_in[3];
    const float* w2      = (const float*)d_in[4];
    const float* b2      = (const float*)d_in[5];
    float* out = (float*)d_out;

    char* ws = (char*)d_ws;
    float* partial = (float*)(ws + O_PART);
    float* h       = (float*)(ws + O_H);
    float* boxes   = (float*)(ws + O_BOXES);
    float* conf    = (float*)(ws + O_CONF);
    unsigned long long* keys = (unsigned long long*)(ws + O_KEYS);
    int* rpart     = (int*)(ws + O_RPART);
    int* order     = (int*)(ws + O_ORDER);
    float* sbox    = (float*)(ws + O_SBOX);
    float* sarea   = (float*)(ws + O_SAREA);
    int* Vcnt      = (int*)(ws + O_VCNT);
    unsigned long long* mask  = (unsigned long long*)(ws + O_MASK);
    unsigned long long* keepw = (unsigned long long*)(ws + O_KEEPW);

    hipMemsetAsync(Vcnt, 0, sizeof(int), stream);

    conv1_kernel<<<dim3(32, 4, 4), 256, 0, stream>>>(feat, w1, partial);
    conv1_reduce<<<1024, 256, 0, stream>>>(partial, b1, h);
    conv2_decode<<<36, 256, 0, stream>>>(h, w2, b2, anchors, boxes, conf, keys, Vcnt);
    rank_partial<<<dim3(36, 36), 256, 0, stream>>>(keys, rpart);
    rank_reduce<<<36, 256, 0, stream>>>(rpart, order);
    gather_sorted<<<36, 256, 0, stream>>>(order, boxes, sbox, sarea);
    nms_mask<<<NBOX, 256, 0, stream>>>(sbox, sarea, Vcnt, mask);
    nms_scan<<<1, 64, 0, stream>>>(mask, Vcnt, keepw);
    finalize<<<36, 256, 0, stream>>>(order, Vcnt, keepw, boxes, conf, out);
}